// Round 1
// baseline (232.455 us; speedup 1.0000x reference)
//
#include <hip/hip_runtime.h>

// RNN_53214644797476: out = tanh(X @ W^T + hs @ H^T), hs never updated.
// => one GEMM [32768,1024]x[1024,1024]^T + tiny h_term GEMM + tanh epilogue.
// fp32 I/O; no fp32 MFMA on CDNA4 -> convert to bf16, MFMA 16x16x32.

typedef __bf16 bf16x8 __attribute__((ext_vector_type(8)));
typedef float f32x4 __attribute__((ext_vector_type(4)));
typedef unsigned short ushort8 __attribute__((ext_vector_type(8)));

constexpr int SEQ = 512, BATCH = 64;
constexpr int M_TOT = SEQ * BATCH;  // 32768
constexpr int K_D = 1024;
constexpr int N_D = 1024;

__device__ __forceinline__ void async16(const void* g, void* l) {
  __builtin_amdgcn_global_load_lds(
      (const __attribute__((address_space(1))) unsigned int*)g,
      (__attribute__((address_space(3))) unsigned int*)l, 16, 0, 0);
}

__device__ __forceinline__ unsigned short f2bf(float f) {
  unsigned int u = __float_as_uint(f);
  u += 0x7FFFu + ((u >> 16) & 1u);  // round-to-nearest-even
  return (unsigned short)(u >> 16);
}

// ---- f32 -> bf16 conversion, 8 elems/thread, grid-stride ----
__global__ __launch_bounds__(256) void cvt_f32_bf16(
    const float* __restrict__ in, unsigned short* __restrict__ out, int n8) {
  int stride = gridDim.x * blockDim.x;
  for (int i = blockIdx.x * blockDim.x + threadIdx.x; i < n8; i += stride) {
    const float4* p = reinterpret_cast<const float4*>(in + (size_t)i * 8);
    float4 a = p[0], b = p[1];
    ushort8 v;
    v[0] = f2bf(a.x); v[1] = f2bf(a.y); v[2] = f2bf(a.z); v[3] = f2bf(a.w);
    v[4] = f2bf(b.x); v[5] = f2bf(b.y); v[6] = f2bf(b.z); v[7] = f2bf(b.w);
    *reinterpret_cast<ushort8*>(out + (size_t)i * 8) = v;
  }
}

// ---- h_term[b][h] = sum_k hs[b][k] * H[h][k] ; one block per h ----
__global__ __launch_bounds__(256) void hterm_kernel(
    const float* __restrict__ hs, const float* __restrict__ Hm,
    float* __restrict__ ht) {
  int h = blockIdx.x;
  __shared__ float Hrow[1024];
  for (int i = threadIdx.x; i < 1024; i += 256)
    Hrow[i] = Hm[(size_t)h * 1024 + i];
  __syncthreads();
  int w = threadIdx.x >> 6, l = threadIdx.x & 63;
  for (int b = w; b < 64; b += 4) {
    float s = 0.f;
    const float* hb = hs + (size_t)b * 1024;
    for (int k = l; k < 1024; k += 64) s += hb[k] * Hrow[k];
#pragma unroll
    for (int off = 32; off > 0; off >>= 1) s += __shfl_down(s, off, 64);
    if (l == 0) ht[b * 1024 + h] = s;
  }
}

// ---- main GEMM: C = tanh(A[M,K](bf16) . B[N,K](bf16)^T + ht[b][n]) ----
// 128x128 tile, BK=32, 4 waves (2x2), 16 MFMA 16x16x32 per wave per K-step.
__global__ __launch_bounds__(256, 2) void gemm_tanh(
    const unsigned short* __restrict__ A, const unsigned short* __restrict__ B,
    const float* __restrict__ ht, float* __restrict__ out0,
    float* __restrict__ out1) {
  __shared__ unsigned short As[128 * 32];
  __shared__ unsigned short Bs[128 * 32];

  // XCD-aware bijective swizzle (nwg = 2048, divisible by 8)
  int bid = blockIdx.x;
  int swz = (bid & 7) * 256 + (bid >> 3);
  int bm = swz >> 3;  // 0..255  (M tiles)
  int bn = swz & 7;   // 0..7    (N tiles)

  int tid = threadIdx.x;
  int lane = tid & 63, wid = tid >> 6;
  int wr = wid >> 1, wc = wid & 1;
  int fr = lane & 15, kq = lane >> 4;

  f32x4 acc[4][4] = {};

  // staging: 128x32 bf16 tile = 512 x 16B chunks; chunk c -> row c>>2, kcol (c&3)*8
  int c1 = tid + 256;
  const unsigned short* gA0 = A + (size_t)(bm * 128 + (tid >> 2)) * 1024 + (tid & 3) * 8;
  const unsigned short* gA1 = A + (size_t)(bm * 128 + (c1 >> 2)) * 1024 + (c1 & 3) * 8;
  const unsigned short* gB0 = B + (size_t)(bn * 128 + (tid >> 2)) * 1024 + (tid & 3) * 8;
  const unsigned short* gB1 = B + (size_t)(bn * 128 + (c1 >> 2)) * 1024 + (c1 & 3) * 8;
  unsigned short* lA0 = &As[tid * 8];
  unsigned short* lA1 = &As[c1 * 8];
  unsigned short* lB0 = &Bs[tid * 8];
  unsigned short* lB1 = &Bs[c1 * 8];

  for (int ks = 0; ks < K_D; ks += 32) {
    async16(gA0 + ks, lA0);
    async16(gA1 + ks, lA1);
    async16(gB0 + ks, lB0);
    async16(gB1 + ks, lB1);
    __syncthreads();  // drains vmcnt before LDS reads

    bf16x8 af[4], bg[4];
#pragma unroll
    for (int mi = 0; mi < 4; ++mi)
      af[mi] = *reinterpret_cast<const bf16x8*>(
          &As[(wr * 64 + mi * 16 + fr) * 32 + kq * 8]);
#pragma unroll
    for (int ni = 0; ni < 4; ++ni)
      bg[ni] = *reinterpret_cast<const bf16x8*>(
          &Bs[(wc * 64 + ni * 16 + fr) * 32 + kq * 8]);
#pragma unroll
    for (int mi = 0; mi < 4; ++mi)
#pragma unroll
      for (int ni = 0; ni < 4; ++ni)
        acc[mi][ni] = __builtin_amdgcn_mfma_f32_16x16x32_bf16(
            af[mi], bg[ni], acc[mi][ni], 0, 0, 0);
    __syncthreads();  // before next stage overwrites LDS
  }

  // epilogue: y = tanh(acc + ht[m%64][n]); write out0, and out1 for last 64 rows
  const int nbase = bn * 128 + wc * 64;
#pragma unroll
  for (int mi = 0; mi < 4; ++mi) {
#pragma unroll
    for (int r = 0; r < 4; ++r) {
      int mloc = wr * 64 + mi * 16 + kq * 4 + r;  // 0..127
      size_t m = (size_t)bm * 128 + mloc;
      int b = mloc & 63;  // m % 64
#pragma unroll
      for (int ni = 0; ni < 4; ++ni) {
        int n = nbase + ni * 16 + fr;
        float x = acc[mi][ni][r] + ht[b * 1024 + n];
        float e = __expf(2.0f * x);
        float y = 1.0f - 2.0f / (e + 1.0f);  // tanh(x), safe at +-inf
        out0[m * 1024 + n] = y;
        if (m >= (size_t)(M_TOT - 64))
          out1[(m - (M_TOT - 64)) * 1024 + n] = y;
      }
    }
  }
}

extern "C" void kernel_launch(void* const* d_in, const int* in_sizes, int n_in,
                              void* d_out, int out_size, void* d_ws,
                              size_t ws_size, hipStream_t stream) {
  (void)in_sizes; (void)n_in; (void)out_size; (void)ws_size;
  const float* X  = (const float*)d_in[0];  // [512,64,1024]
  const float* hs = (const float*)d_in[1];  // [64,1024]
  const float* W  = (const float*)d_in[2];  // [1024,1024]
  const float* Hm = (const float*)d_in[3];  // [1024,1024]
  float* out0 = (float*)d_out;                       // [32768,1024]
  float* out1 = out0 + (size_t)M_TOT * N_D;          // [64,1024]

  // ws layout: Xbf (64 MiB) | Wbf (2 MiB) | hterm (256 KiB)  ~= 69.5 MB
  unsigned short* Xbf = (unsigned short*)d_ws;
  unsigned short* Wbf = Xbf + (size_t)M_TOT * K_D;
  float* hterm = (float*)(Wbf + (size_t)N_D * K_D);

  cvt_f32_bf16<<<2048, 256, 0, stream>>>(X, Xbf, M_TOT * K_D / 8);
  cvt_f32_bf16<<<512, 256, 0, stream>>>(W, Wbf, N_D * K_D / 8);
  hterm_kernel<<<1024, 256, 0, stream>>>(hs, Hm, hterm);
  gemm_tanh<<<2048, 256, 0, stream>>>(Xbf, Wbf, hterm, out0, out1);
}